// Round 21
// baseline (146.942 us; speedup 1.0000x reference)
//
#include <hip/hip_runtime.h>
#include <hip/hip_bf16.h>

// Shapes (fixed by the problem)
constexpr int CB = 4, CS = 2048, CD = 768, CH = 4, CDH = 192;
constexpr int CM = CB * CS;  // 8192 rows

typedef float f32x4 __attribute__((ext_vector_type(4)));
typedef float fx4 __attribute__((ext_vector_type(4)));
typedef __bf16 bx8 __attribute__((ext_vector_type(8)));
typedef unsigned short u16;
typedef u16 u16x8 __attribute__((ext_vector_type(8)));
typedef u16 u16x4 __attribute__((ext_vector_type(4)));

static __device__ __forceinline__ u16 f32_bf16(float f) {
  unsigned u = __builtin_bit_cast(unsigned, f);
  u += 0x7FFFu + ((u >> 16) & 1u);
  return (u16)(u >> 16);
}
static __device__ __forceinline__ float bf16_f32(u16 v) {
  return __builtin_bit_cast(float, (unsigned)v << 16);
}

static __device__ __forceinline__ f32x4 mfma16(bx8 a, bx8 b, f32x4 c) {
  return __builtin_amdgcn_mfma_f32_16x16x32_bf16(a, b, c, 0, 0, 0);
}

// Raw barriers (T4, proven r12): __syncthreads() emits s_waitcnt vmcnt(0)
// lgkmcnt(0) before s_barrier, draining in-flight global prefetch.
static __device__ __forceinline__ void bar_bare() {
  __builtin_amdgcn_s_barrier();
  __builtin_amdgcn_sched_barrier(0);
}
static __device__ __forceinline__ void bar_lgkm() {
  asm volatile("s_waitcnt lgkmcnt(0)" ::: "memory");
  __builtin_amdgcn_s_barrier();
  __builtin_amdgcn_sched_barrier(0);
}

// ---------------------------------------------------------------- convert
__global__ void __launch_bounds__(256) convert_all(
    const float* __restrict__ x, const float* __restrict__ wq,
    const float* __restrict__ wk, const float* __restrict__ wv,
    const float* __restrict__ wo, u16* __restrict__ xb, u16* __restrict__ wqb,
    u16* __restrict__ wkb, u16* __restrict__ wvb, u16* __restrict__ wob) {
  const float* srcs[5] = {x, wq, wk, wv, wo};
  u16* dsts[5] = {xb, wqb, wkb, wvb, wob};
  const int n4s[5] = {CM * CD / 4, CD * CD / 4, CD * CD / 4, CD * CD / 4,
                      CD * CD / 4};
  const int gsz = gridDim.x * blockDim.x;
  const int gid = blockIdx.x * blockDim.x + threadIdx.x;
#pragma unroll
  for (int sg = 0; sg < 5; ++sg) {
    const fx4* src = (const fx4*)srcs[sg];
    u16* dst = dsts[sg];
    const int n4 = n4s[sg];
    for (int i = gid; i < n4; i += gsz) {
      fx4 v = src[i];
      u16x4 o;
      o[0] = f32_bf16(v[0]);
      o[1] = f32_bf16(v[1]);
      o[2] = f32_bf16(v[2]);
      o[3] = f32_bf16(v[3]);
      *(u16x4*)&dst[(size_t)i * 4] = o;
    }
  }
}

// ---------------------------------------------------------------- GEMM
// r12 version (best measured): 128x128 tile, reg-prefetch + raw barriers.
// Closed: gload_lds (r10, -6us), launch_bounds(,3) (r19, neutral),
// 128x64 tile (r20, -3us).
template <bool OUT_BF16>
__global__ void __launch_bounds__(256) gemm_bt(
    const u16* __restrict__ A, const u16* __restrict__ Bw0,
    const u16* __restrict__ Bw1, const u16* __restrict__ Bw2,
    void* __restrict__ C0, void* __restrict__ C1, void* __restrict__ C2,
    int M, int N, int K) {
  constexpr int LDK = 72;
  __shared__ u16 As[128][LDK];
  __shared__ u16 Bs[128][LDK];
  const int z = blockIdx.z;
  const u16* Bw = (z == 0) ? Bw0 : ((z == 1) ? Bw1 : Bw2);
  void* Cv = (z == 0) ? C0 : ((z == 1) ? C1 : C2);
  const int m0 = blockIdx.x * 128;
  const int n0 = blockIdx.y * 128;
  const int tid = threadIdx.x;
  const int wave = tid >> 6, lane = tid & 63;
  const int wr = wave >> 1, wc = wave & 1;
  const int lr = lane & 15, lhi = lane >> 4;

  f32x4 acc[4][4];
  const f32x4 zero = {0.f, 0.f, 0.f, 0.f};
#pragma unroll
  for (int i = 0; i < 4; ++i)
#pragma unroll
    for (int j = 0; j < 4; ++j) acc[i][j] = zero;

  u16x8 areg[4], breg[4];
  auto ldregs = [&](int kk) {
#pragma unroll
    for (int r = 0; r < 4; ++r) {
      const int id = tid + r * 256;
      const int row = id >> 3, ch = id & 7;
      areg[r] = *(const u16x8*)&A[(size_t)(m0 + row) * K + kk + ch * 8];
      breg[r] = *(const u16x8*)&Bw[(size_t)(n0 + row) * K + kk + ch * 8];
    }
  };

  ldregs(0);
  for (int kk = 0; kk < K; kk += 64) {
    bar_bare();
#pragma unroll
    for (int r = 0; r < 4; ++r) {
      const int id = tid + r * 256;
      const int row = id >> 3, ch = id & 7;
      *(u16x8*)&As[row][ch * 8] = areg[r];
      *(u16x8*)&Bs[row][ch * 8] = breg[r];
    }
    if (kk + 64 < K) ldregs(kk + 64);
    bar_lgkm();
#pragma unroll
    for (int ks = 0; ks < 2; ++ks) {
      bx8 af[4], bf[4];
#pragma unroll
      for (int mf = 0; mf < 4; ++mf)
        af[mf] = *(const bx8*)&As[wr * 64 + mf * 16 + lr][ks * 32 + lhi * 8];
#pragma unroll
      for (int nf = 0; nf < 4; ++nf)
        bf[nf] = *(const bx8*)&Bs[wc * 64 + nf * 16 + lr][ks * 32 + lhi * 8];
      __builtin_amdgcn_s_setprio(1);
#pragma unroll
      for (int mf = 0; mf < 4; ++mf)
#pragma unroll
        for (int nf = 0; nf < 4; ++nf)
          acc[mf][nf] = mfma16(af[mf], bf[nf], acc[mf][nf]);
      __builtin_amdgcn_s_setprio(0);
    }
  }
#pragma unroll
  for (int mf = 0; mf < 4; ++mf)
#pragma unroll
    for (int nf = 0; nf < 4; ++nf)
#pragma unroll
      for (int r = 0; r < 4; ++r) {
        const int row = m0 + wr * 64 + mf * 16 + lhi * 4 + r;
        const int col = n0 + wc * 64 + nf * 16 + lr;
        if constexpr (OUT_BF16)
          ((u16*)Cv)[(size_t)row * N + col] = f32_bf16(acc[mf][nf][r]);
        else
          ((float*)Cv)[(size_t)row * N + col] = acc[mf][nf][r];
      }
}

// ---------------------------------------------------------------- flash attn
// r21 = r15's per-wave body (pi-permuted PV, raw barriers) in 8-WAVE blocks
// (QBLK=128): all waves read the SAME K/V fragments, so one shared stage
// serves 128 q-rows -> staging ds_writes + global fetch per unit work halve,
// and (if VGPR<=128) 2 blocks/CU = 4 waves/SIMD doubles latency overlap.
// This is r13 minus its failure mode: r13's (512,4) cap forced 64 VGPRs ->
// spill; the pi body needs only ~116 (r17) and staging regs drop 48->24 at
// 512 threads, so NATURAL allocation (no min-waves bound) should fit 128.
// LDS 24,576 B/block. Work split: r11's VERIFIED FA_TBL (32 balanced
// chunks/bh, <=3 partials, all slots always written) + r11's combine.
#define PKE(q, k0, k1, p)                                               \
  ((unsigned)(q) | ((unsigned)(k0) << 4) | ((unsigned)(k1) << 9) |      \
   ((unsigned)((p) + 1) << 15))
__device__ const unsigned FA_TBL[32] = {
    PKE(10, 0, 11, 0),   PKE(10, 11, 22, 1),  PKE(15, 0, 11, 2),
    PKE(15, 11, 22, 3),  PKE(4, 0, 10, -1),   PKE(9, 0, 10, 4),
    PKE(9, 10, 20, 5),   PKE(13, 0, 10, 6),   PKE(14, 0, 10, 7),
    PKE(14, 10, 20, 8),  PKE(14, 20, 30, 9),  PKE(15, 22, 32, 10),
    PKE(8, 0, 9, 11),    PKE(8, 9, 18, 12),   PKE(12, 0, 9, 13),
    PKE(12, 9, 18, 14),  PKE(0, 0, 2, -1),    PKE(1, 0, 4, -1),
    PKE(2, 0, 6, -1),    PKE(5, 0, 6, 15),    PKE(5, 6, 12, 16),
    PKE(6, 0, 7, 17),    PKE(6, 7, 14, 18),   PKE(3, 0, 8, -1),
    PKE(7, 0, 8, 19),    PKE(7, 8, 16, 20),   PKE(11, 0, 8, 21),
    PKE(11, 8, 16, 22),  PKE(11, 16, 24, 23), PKE(12, 18, 26, 24),
    PKE(13, 10, 19, 25), PKE(13, 19, 28, 26)};

__global__ void __launch_bounds__(512) flash_attn(
    const u16* __restrict__ Qg, const u16* __restrict__ Kg,
    const u16* __restrict__ Vg, u16* __restrict__ Og, u16* __restrict__ pO,
    float* __restrict__ pML) {
  __shared__ u16 Ks[12288];
  __shared__ u16 Vs[12288];
  const int i0_ = blockIdx.x;
  const int xcd = i0_ & 7;  // presumed XCD (block -> XCD = id % 8)
  const int r_ = i0_ >> 3;  // 0..63
  const int bh = xcd * 2 + (r_ & 1);
  const int s = r_ >> 1;  // 0..31
  const unsigned e = FA_TBL[s];
  const int q128 = (int)(e & 15u);
  const int kt0 = (int)((e >> 4) & 31u);
  const int kt1 = (int)((e >> 9) & 63u);
  const int pidx = (int)((e >> 15) & 63u) - 1;
  const int b = bh >> 2, h = bh & 3;
  const int tid = threadIdx.x;
  const int wave = tid >> 6, lane = tid & 63;
  const int lr = lane & 15, lhi = lane >> 4;
  const size_t base_elem = ((size_t)b * CS) * CD + (size_t)h * CDH;
  constexpr float scale = 0.07216878364870323f;  // 1/sqrt(192)
  const f32x4 zero = {0.f, 0.f, 0.f, 0.f};

  // staging offsets: 3 rounds x 512 threads cover the 64x192 tile.
  // K: linear dest + inverse-XOR-swizzled source (rule #21).
  // V: subtiled 4k x 16d dest; source row = pi^{-1}(position) (r14-proven).
  int kOff[3], vOff[3];
#pragma unroll
  for (int r = 0; r < 3; ++r) {
    const int p = tid + r * 512;
    {
      const int k = p / 24, c16 = p - k * 24;
      const unsigned swz = ((unsigned)(c16 * 16)) ^ ((unsigned)((k & 7) << 4));
      kOff[r] = k * CD + (int)(swz >> 1);
    }
    {
      const int blk = p >> 3, kq = (p >> 1) & 3, dh = p & 1;
      const int kpos = ((blk & 15) << 2) + kq;  // position in pi space
      const int kglob = (((kpos >> 5) * 2 + ((kpos >> 2) & 1)) << 4) +
                        (((kpos >> 3) & 3) << 2) + (kpos & 3);
      const int d = ((blk >> 4) << 4) + dh * 8;
      vOff[r] = kglob * CD + d;
    }
  }
  const unsigned vlds0 =
      (unsigned)(unsigned long long)(__attribute__((address_space(3)))
                                         u16*)&Vs[0];

  float m_run = -INFINITY, l_run = 0.f;
  f32x4 acc[12];
#pragma unroll
  for (int nf = 0; nf < 12; ++nf) acc[nf] = zero;

  // Q fragments: wave w owns q-rows [q128*128 + w*16, +16)
  bx8 qf[6];
  {
    const size_t qoff =
        base_elem + (size_t)(q128 * 128 + wave * 16 + lr) * CD;
#pragma unroll
    for (int c = 0; c < 6; ++c)
      qf[c] = *(const bx8*)&Qg[qoff + c * 32 + lhi * 8];
  }

  u16x8 kreg[3], vreg[3];
  auto ldregs = [&](int kt) {
    const u16* kg = Kg + base_elem + (size_t)(kt * 64) * CD;
    const u16* vg = Vg + base_elem + (size_t)(kt * 64) * CD;
#pragma unroll
    for (int r = 0; r < 3; ++r) {
      kreg[r] = *(const u16x8*)&kg[kOff[r]];
      vreg[r] = *(const u16x8*)&vg[vOff[r]];
    }
  };

  const int qg_row = q128 * 128 + wave * 16 + lr;
  ldregs(kt0);

  for (int kt = kt0; kt < kt1; ++kt) {
    bar_bare();  // previous tile's LDS reads consumed before arrival
#pragma unroll
    for (int r = 0; r < 3; ++r) {
      *(u16x8*)&Ks[(size_t)(tid + r * 512) * 8] = kreg[r];
      *(u16x8*)&Vs[(size_t)(tid + r * 512) * 8] = vreg[r];
    }
    if (kt + 1 < kt1) ldregs(kt + 1);  // stays in flight across bar_lgkm
    bar_lgkm();  // ds_writes visible; prefetch NOT drained

    const int k0 = kt * 64;
    const bool diag = (kt >= 2 * q128);
    f32x4 st[4];
#pragma unroll
    for (int mf = 0; mf < 4; ++mf) st[mf] = zero;
    __builtin_amdgcn_s_setprio(1);
#pragma unroll
    for (int c = 0; c < 6; ++c)
#pragma unroll
      for (int mf = 0; mf < 4; ++mf) {
        const int row = mf * 16 + lr;
        const unsigned off =
            ((unsigned)(c * 64 + lhi * 16)) ^ ((unsigned)((row & 7) << 4));
        const bx8 kf =
            *(const bx8*)((const char*)Ks + (size_t)row * 384 + off);
        st[mf] = mfma16(kf, qf[c], st[mf]);
      }
    __builtin_amdgcn_s_setprio(0);
    float pvv[16];
#pragma unroll
    for (int mf = 0; mf < 4; ++mf)
#pragma unroll
      for (int r = 0; r < 4; ++r) {
        float sv = st[mf][r] * scale;
        if (diag && (k0 + mf * 16 + lhi * 4 + r > qg_row)) sv = -INFINITY;
        pvv[mf * 4 + r] = sv;
      }
    float mx = pvv[0];
#pragma unroll
    for (int tt = 1; tt < 16; ++tt) mx = fmaxf(mx, pvv[tt]);
    mx = fmaxf(mx, __shfl_xor(mx, 16, 64));
    mx = fmaxf(mx, __shfl_xor(mx, 32, 64));
    const bool skip = __all(mx - m_run <= 8.0f);
    if (!skip) {
      const float mnew = fmaxf(m_run, mx);
      const float alpha = __expf(m_run - mnew);
      float afr[4];
#pragma unroll
      for (int r = 0; r < 4; ++r) afr[r] = __shfl(alpha, lhi * 4 + r, 64);
#pragma unroll
      for (int nf = 0; nf < 12; ++nf)
#pragma unroll
        for (int r = 0; r < 4; ++r) acc[nf][r] *= afr[r];
      l_run *= alpha;
      m_run = mnew;
    }
    float rs = 0.f;
#pragma unroll
    for (int tt = 0; tt < 16; ++tt) {
      const float e2 = __expf(pvv[tt] - m_run);
      pvv[tt] = e2;
      rs += e2;
    }
    rs += __shfl_xor(rs, 16, 64);
    rs += __shfl_xor(rs, 32, 64);
    l_run += rs;
    // pi-permuted A-fragments: lane-local, no LDS, no shuffles.
    u16x8 pa0, pa1;
#pragma unroll
    for (int j = 0; j < 8; ++j) {
      pa0[j] = f32_bf16(pvv[j]);
      pa1[j] = f32_bf16(pvv[8 + j]);
    }
    const bx8 pf0 = __builtin_bit_cast(bx8, pa0);
    const bx8 pf1 = __builtin_bit_cast(bx8, pa1);
#pragma unroll
    for (int gg = 0; gg < 3; ++gg) {
      u16x4 tl[4][2], th[4][2];
#pragma unroll
      for (int q4 = 0; q4 < 4; ++q4)
#pragma unroll
        for (int c2 = 0; c2 < 2; ++c2) {
          const int nf = gg * 4 + q4;
          const unsigned va =
              vlds0 + (unsigned)((nf * 16 + c2 * 8 + lhi * 2) * 128 + lr * 8);
          asm volatile("ds_read_b64_tr_b16 %0, %2\n\t"
                       "ds_read_b64_tr_b16 %1, %2 offset:128"
                       : "=&v"(tl[q4][c2]), "=&v"(th[q4][c2])
                       : "v"(va));
        }
      asm volatile("s_waitcnt lgkmcnt(0)" ::: "memory");
      __builtin_amdgcn_sched_barrier(0);
      __builtin_amdgcn_s_setprio(1);
#pragma unroll
      for (int q4 = 0; q4 < 4; ++q4)
#pragma unroll
        for (int c2 = 0; c2 < 2; ++c2) {
          const int nf = gg * 4 + q4;
          const u16x8 vv = __builtin_shufflevector(tl[q4][c2], th[q4][c2], 0,
                                                   1, 2, 3, 4, 5, 6, 7);
          acc[nf] = mfma16(c2 == 0 ? pf0 : pf1, __builtin_bit_cast(bx8, vv),
                           acc[nf]);
        }
      __builtin_amdgcn_s_setprio(0);
    }
  }

  if (pidx < 0) {
    // final: write normalized O to preout
#pragma unroll
    for (int r = 0; r < 4; ++r) {
      const float lb = __shfl(l_run, lhi * 4 + r, 64);
      const float linv = 1.0f / lb;
      const size_t orow =
          base_elem +
          (size_t)(q128 * 128 + wave * 16 + lhi * 4 + r) * CD;
#pragma unroll
      for (int nf = 0; nf < 12; ++nf)
        Og[orow + nf * 16 + lr] = f32_bf16(acc[nf][r] * linv);
    }
  } else {
    const int pbase = bh * 27 + pidx;
    if (lhi == 0) {
      pML[pbase * 256 + wave * 16 + lr] = m_run;
      pML[pbase * 256 + 128 + wave * 16 + lr] = l_run;
    }
#pragma unroll
    for (int r = 0; r < 4; ++r) {
      const float lb = __shfl(l_run, lhi * 4 + r, 64);
      const float linv = 1.0f / lb;
      u16* dst =
          pO + ((size_t)pbase * 128 + wave * 16 + lhi * 4 + r) * 192;
#pragma unroll
      for (int nf = 0; nf < 12; ++nf)
        dst[nf * 16 + lr] = f32_bf16(acc[nf][r] * linv);
    }
  }
}

// ---------------------------------------------------------------- combine
// r11's verified combine: merge 2-3 partials per q-tile (q 5..15). All
// partial slots are written every launch -> no uninitialized reads.
#define CBE(n, p0, p1, p2) \
  ((unsigned)(n) | ((unsigned)(p0) << 2) | ((unsigned)(p1) << 8) | \
   ((unsigned)(p2) << 14))
__device__ const unsigned CB_TBL[11] = {
    CBE(2, 15, 16, 0), CBE(2, 17, 18, 0), CBE(2, 19, 20, 0),
    CBE(2, 11, 12, 0), CBE(2, 4, 5, 0),   CBE(2, 0, 1, 0),
    CBE(3, 21, 22, 23), CBE(3, 13, 14, 24), CBE(3, 6, 25, 26),
    CBE(3, 7, 8, 9),    CBE(3, 2, 3, 10)};

__global__ void __launch_bounds__(256) combine_qt(
    const u16* __restrict__ pO, const float* __restrict__ pML,
    u16* __restrict__ Og) {
  const int cb = blockIdx.x;  // 176 = 16 bh x 11 q-tiles
  const int bh = cb / 11, qi = cb % 11;
  const int q128 = qi + 5;
  const unsigned e = CB_TBL[qi];
  const int n = (int)(e & 3u);
  const int pid0 = (int)((e >> 2) & 63u);
  const int pid1 = (int)((e >> 8) & 63u);
  const int pid2 = (int)((e >> 14) & 63u);
  const int b = bh >> 2, h = bh & 3;
  const int tid = threadIdx.x;
  const int row = tid >> 1, half = tid & 1;
  float m[3], l[3];
  const int pids[3] = {pid0, pid1, pid2};
  for (int i = 0; i < n; ++i) {
    m[i] = pML[(bh * 27 + pids[i]) * 256 + row];
    l[i] = pML[(bh * 27 + pids[i]) * 256 + 128 + row];
  }
  float M = m[0];
  for (int i = 1; i < n; ++i) M = fmaxf(M, m[i]);
  float w[3], wsum = 0.f;
  for (int i = 0; i < n; ++i) {
    w[i] = l[i] * __expf(m[i] - M);
    wsum += w[i];
  }
  const float inv = 1.0f / wsum;
  const size_t obase =
      ((size_t)b * CS + (size_t)q128 * 128 + row) * CD + h * CDH + half * 96;
#pragma unroll
  for (int c = 0; c < 12; ++c) {
    float a8[8] = {0.f, 0.f, 0.f, 0.f, 0.f, 0.f, 0.f, 0.f};
    for (int i = 0; i < n; ++i) {
      const u16x8 v = *(const u16x8*)&pO[((size_t)(bh * 27 + pids[i]) * 128 +
                                          row) *
                                             192 +
                                         half * 96 + c * 8];
      const float f = w[i] * inv;
#pragma unroll
      for (int j = 0; j < 8; ++j) a8[j] += f * bf16_f32(v[j]);
    }
    u16x8 o;
#pragma unroll
    for (int j = 0; j < 8; ++j) o[j] = f32_bf16(a8[j]);
    *(u16x8*)&Og[obase + c * 8] = o;
  }
}

// ---------------------------------------------------------------- launch
extern "C" void kernel_launch(void* const* d_in, const int* in_sizes, int n_in,
                              void* d_out, int out_size, void* d_ws,
                              size_t ws_size, hipStream_t stream) {
  (void)in_sizes;
  (void)n_in;
  (void)out_size;
  (void)ws_size;
  const float* x = (const float*)d_in[0];
  const float* wq = (const float*)d_in[1];
  const float* wk = (const float*)d_in[2];
  const float* wv = (const float*)d_in[3];
  const float* wo = (const float*)d_in[4];
  float* out = (float*)d_out;
  char* ws = (char*)d_ws;
  const size_t big = (size_t)CM * CD * 2;  // 12,582,912 B
  const size_t wsz = (size_t)CD * CD * 2;  // 1,179,648 B
  u16* xb = (u16*)ws;  // reused as preout after QKV gemm
  u16* qb = (u16*)(ws + big);
  u16* kb = (u16*)(ws + 2 * big);
  u16* vb = (u16*)(ws + 3 * big);
  u16* wqb = (u16*)(ws + 4 * big);
  u16* wkb = (u16*)(ws + 4 * big + wsz);
  u16* wvb = (u16*)(ws + 4 * big + 2 * wsz);
  u16* wob = (u16*)(ws + 4 * big + 3 * wsz);
  u16* pob = xb;
  // partial scratch in d_out (25.17 MB): pO 21.23 MB + pML 0.44 MB
  u16* pO = (u16*)d_out;
  float* pML = (float*)((char*)d_out + (size_t)16 * 27 * 128 * 192 * 2);

  convert_all<<<dim3(2048), dim3(256), 0, stream>>>(x, wq, wk, wv, wo, xb, wqb,
                                                    wkb, wvb, wob);
  gemm_bt<true><<<dim3(64, 6, 3), dim3(256), 0, stream>>>(
      xb, wqb, wkb, wvb, (void*)qb, (void*)kb, (void*)vb, CM, CD, CD);
  flash_attn<<<dim3(512), dim3(512), 0, stream>>>(qb, kb, vb, pob, pO, pML);
  combine_qt<<<dim3(176), dim3(256), 0, stream>>>(pO, pML, pob);
  gemm_bt<false><<<dim3(64, 6, 1), dim3(256), 0, stream>>>(
      pob, wob, wob, wob, (void*)out, (void*)out, (void*)out, CM, CD, CD);
}

// Round 22
// 132.447 us; speedup vs baseline: 1.1094x; 1.1094x over previous
//
#include <hip/hip_runtime.h>
#include <hip/hip_bf16.h>

// Shapes (fixed by the problem)
constexpr int CB = 4, CS = 2048, CD = 768, CH = 4, CDH = 192;
constexpr int CM = CB * CS;  // 8192 rows

typedef float f32x4 __attribute__((ext_vector_type(4)));
typedef float fx4 __attribute__((ext_vector_type(4)));
typedef __bf16 bx8 __attribute__((ext_vector_type(8)));
typedef unsigned short u16;
typedef u16 u16x8 __attribute__((ext_vector_type(8)));
typedef u16 u16x4 __attribute__((ext_vector_type(4)));

static __device__ __forceinline__ u16 f32_bf16(float f) {
  unsigned u = __builtin_bit_cast(unsigned, f);
  u += 0x7FFFu + ((u >> 16) & 1u);
  return (u16)(u >> 16);
}
static __device__ __forceinline__ float bf16_f32(u16 v) {
  return __builtin_bit_cast(float, (unsigned)v << 16);
}

static __device__ __forceinline__ f32x4 mfma16(bx8 a, bx8 b, f32x4 c) {
  return __builtin_amdgcn_mfma_f32_16x16x32_bf16(a, b, c, 0, 0, 0);
}

// Raw barriers (T4, proven r12): __syncthreads() emits s_waitcnt vmcnt(0)
// lgkmcnt(0) before s_barrier, draining in-flight global prefetch.
static __device__ __forceinline__ void bar_bare() {
  __builtin_amdgcn_s_barrier();
  __builtin_amdgcn_sched_barrier(0);
}
static __device__ __forceinline__ void bar_lgkm() {
  asm volatile("s_waitcnt lgkmcnt(0)" ::: "memory");
  __builtin_amdgcn_s_barrier();
  __builtin_amdgcn_sched_barrier(0);
}

// ---------------------------------------------------------------- convert
__global__ void __launch_bounds__(256) convert_all(
    const float* __restrict__ x, const float* __restrict__ wq,
    const float* __restrict__ wk, const float* __restrict__ wv,
    const float* __restrict__ wo, u16* __restrict__ xb, u16* __restrict__ wqb,
    u16* __restrict__ wkb, u16* __restrict__ wvb, u16* __restrict__ wob) {
  const float* srcs[5] = {x, wq, wk, wv, wo};
  u16* dsts[5] = {xb, wqb, wkb, wvb, wob};
  const int n4s[5] = {CM * CD / 4, CD * CD / 4, CD * CD / 4, CD * CD / 4,
                      CD * CD / 4};
  const int gsz = gridDim.x * blockDim.x;
  const int gid = blockIdx.x * blockDim.x + threadIdx.x;
#pragma unroll
  for (int sg = 0; sg < 5; ++sg) {
    const fx4* src = (const fx4*)srcs[sg];
    u16* dst = dsts[sg];
    const int n4 = n4s[sg];
    for (int i = gid; i < n4; i += gsz) {
      fx4 v = src[i];
      u16x4 o;
      o[0] = f32_bf16(v[0]);
      o[1] = f32_bf16(v[1]);
      o[2] = f32_bf16(v[2]);
      o[3] = f32_bf16(v[3]);
      *(u16x4*)&dst[(size_t)i * 4] = o;
    }
  }
}

// ---------------------------------------------------------------- GEMM
// r12 version (best measured): 128x128 tile, reg-prefetch + raw barriers.
// Closed: gload_lds (r10, -6us), launch_bounds(,3) (r19, neutral),
// 128x64 tile (r20, -3us).
template <bool OUT_BF16>
__global__ void __launch_bounds__(256) gemm_bt(
    const u16* __restrict__ A, const u16* __restrict__ Bw0,
    const u16* __restrict__ Bw1, const u16* __restrict__ Bw2,
    void* __restrict__ C0, void* __restrict__ C1, void* __restrict__ C2,
    int M, int N, int K) {
  constexpr int LDK = 72;
  __shared__ u16 As[128][LDK];
  __shared__ u16 Bs[128][LDK];
  const int z = blockIdx.z;
  const u16* Bw = (z == 0) ? Bw0 : ((z == 1) ? Bw1 : Bw2);
  void* Cv = (z == 0) ? C0 : ((z == 1) ? C1 : C2);
  const int m0 = blockIdx.x * 128;
  const int n0 = blockIdx.y * 128;
  const int tid = threadIdx.x;
  const int wave = tid >> 6, lane = tid & 63;
  const int wr = wave >> 1, wc = wave & 1;
  const int lr = lane & 15, lhi = lane >> 4;

  f32x4 acc[4][4];
  const f32x4 zero = {0.f, 0.f, 0.f, 0.f};
#pragma unroll
  for (int i = 0; i < 4; ++i)
#pragma unroll
    for (int j = 0; j < 4; ++j) acc[i][j] = zero;

  u16x8 areg[4], breg[4];
  auto ldregs = [&](int kk) {
#pragma unroll
    for (int r = 0; r < 4; ++r) {
      const int id = tid + r * 256;
      const int row = id >> 3, ch = id & 7;
      areg[r] = *(const u16x8*)&A[(size_t)(m0 + row) * K + kk + ch * 8];
      breg[r] = *(const u16x8*)&Bw[(size_t)(n0 + row) * K + kk + ch * 8];
    }
  };

  ldregs(0);
  for (int kk = 0; kk < K; kk += 64) {
    bar_bare();
#pragma unroll
    for (int r = 0; r < 4; ++r) {
      const int id = tid + r * 256;
      const int row = id >> 3, ch = id & 7;
      *(u16x8*)&As[row][ch * 8] = areg[r];
      *(u16x8*)&Bs[row][ch * 8] = breg[r];
    }
    if (kk + 64 < K) ldregs(kk + 64);
    bar_lgkm();
#pragma unroll
    for (int ks = 0; ks < 2; ++ks) {
      bx8 af[4], bf[4];
#pragma unroll
      for (int mf = 0; mf < 4; ++mf)
        af[mf] = *(const bx8*)&As[wr * 64 + mf * 16 + lr][ks * 32 + lhi * 8];
#pragma unroll
      for (int nf = 0; nf < 4; ++nf)
        bf[nf] = *(const bx8*)&Bs[wc * 64 + nf * 16 + lr][ks * 32 + lhi * 8];
      __builtin_amdgcn_s_setprio(1);
#pragma unroll
      for (int mf = 0; mf < 4; ++mf)
#pragma unroll
        for (int nf = 0; nf < 4; ++nf)
          acc[mf][nf] = mfma16(af[mf], bf[nf], acc[mf][nf]);
      __builtin_amdgcn_s_setprio(0);
    }
  }
#pragma unroll
  for (int mf = 0; mf < 4; ++mf)
#pragma unroll
    for (int nf = 0; nf < 4; ++nf)
#pragma unroll
      for (int r = 0; r < 4; ++r) {
        const int row = m0 + wr * 64 + mf * 16 + lhi * 4 + r;
        const int col = n0 + wc * 64 + nf * 16 + lr;
        if constexpr (OUT_BF16)
          ((u16*)Cv)[(size_t)row * N + col] = f32_bf16(acc[mf][nf][r]);
        else
          ((float*)Cv)[(size_t)row * N + col] = acc[mf][nf][r];
      }
}

// ---------------------------------------------------------------- flash attn
// FINAL = r15 (best measured, 132.98 us total): pi-permuted PV (no P LDS
// roundtrip), reg-staged, raw barriers, 512 equal-length blocks, XCD remap.
// Closed as neutral/worse: QBLK=128 (r11/r21), occupancy-via-cap (r13/r14
// spills), gload_lds staging (r10/r16), K-dbuf (r9/r18), finer split (r17).
// Invariant: P[q][k] x V[k][d] unchanged under k-permutation applied to both
// P and V. pi(mf*16+lhi*4+r) = lhi*8+(mf&1)*4+r+(mf>>1)*32 makes lane
// (lhi,lr)'s 16 post-softmax values its PV A-fragment in order; V staged
// with inverse-pi'd row offsets (vOff only). LDS 49,152 B.
// 512 EQUAL-LENGTH blocks: pair (qtLo=t, qtHi=31-t); role A = qtLo (final)
// + qtHi prefix (partial); role B = qtHi suffix (partial). XCD remap (T1).
__global__ void __launch_bounds__(256, 2) flash_attn(
    const u16* __restrict__ Qg, const u16* __restrict__ Kg,
    const u16* __restrict__ Vg, u16* __restrict__ Og, u16* __restrict__ paO,
    float* __restrict__ paML, u16* __restrict__ pbO,
    float* __restrict__ pbML) {
  __shared__ u16 Ks[12288];
  __shared__ u16 Vs[12288];
  const int i0_ = blockIdx.x;
  const int xcd = i0_ & 7;        // presumed XCD (block -> XCD = id % 8)
  const int j_ = i0_ >> 3;        // 0..63 within XCD
  const int bh = xcd * 2 + (j_ >> 5);
  const int jj = j_ & 31;
  const int t = jj >> 1;
  const int roleB = jj & 1;
  const int qtLo = t, qtHi = 31 - t;
  const int slot = bh * 16 + (15 - t);
  const int b = bh >> 2, h = bh & 3;
  const int tid = threadIdx.x;
  const int wave = tid >> 6, lane = tid & 63;
  const int lr = lane & 15, lhi = lane >> 4;
  const size_t base_elem = ((size_t)b * CS) * CD + (size_t)h * CDH;
  constexpr float scale = 0.07216878364870323f;  // 1/sqrt(192)
  const f32x4 zero = {0.f, 0.f, 0.f, 0.f};

  // per-thread staging offsets (within a KV tile), elements.
  // K: linear dest + inverse-XOR-swizzled source (rule #21).
  // V: subtiled 4k x 16d dest; source row = pi^{-1}(position) so that the
  //    tr-read's position axis is the pi-permuted k axis.
  int kOff[6], vOff[6];
#pragma unroll
  for (int r = 0; r < 6; ++r) {
    const int p = tid + r * 256;
    {
      const int k = p / 24, c16 = p - k * 24;
      const unsigned swz = ((unsigned)(c16 * 16)) ^ ((unsigned)((k & 7) << 4));
      kOff[r] = k * CD + (int)(swz >> 1);
    }
    {
      const int blk = p >> 3, kq = (p >> 1) & 3, dh = p & 1;
      const int kpos = ((blk & 15) << 2) + kq;  // position in pi space
      // k = pi^{-1}(kpos): pos bits b32|l|m1|r -> k = (b32*2+m1)*16 + l*4 + r
      const int kglob = (((kpos >> 5) * 2 + ((kpos >> 2) & 1)) << 4) +
                        (((kpos >> 3) & 3) << 2) + (kpos & 3);
      const int d = ((blk >> 4) << 4) + dh * 8;
      vOff[r] = kglob * CD + d;
    }
  }
  const unsigned vlds0 =
      (unsigned)(unsigned long long)(__attribute__((address_space(3)))
                                         u16*)&Vs[0];

  float m_run, l_run;
  f32x4 acc[12];
  bx8 qf[6];
  u16x8 kreg[6], vreg[6];

  auto qload = [&](int qt) {
    const size_t qoff = base_elem + (size_t)(qt * 64 + wave * 16 + lr) * CD;
#pragma unroll
    for (int c = 0; c < 6; ++c)
      qf[c] = *(const bx8*)&Qg[qoff + c * 32 + lhi * 8];
  };

  auto ldregs = [&](int kt) {
    const u16* kg = Kg + base_elem + (size_t)(kt * 64) * CD;
    const u16* vg = Vg + base_elem + (size_t)(kt * 64) * CD;
#pragma unroll
    for (int r = 0; r < 6; ++r) {
      kreg[r] = *(const u16x8*)&kg[kOff[r]];
      vreg[r] = *(const u16x8*)&vg[vOff[r]];
    }
  };

  auto compute = [&](int i, int qt) {
    const int qg = qt * 64 + wave * 16 + lr;
    const int k0 = i * 64;
    const bool diag = (i == qt);
    f32x4 st[4];
#pragma unroll
    for (int mf = 0; mf < 4; ++mf) st[mf] = zero;
    __builtin_amdgcn_s_setprio(1);
#pragma unroll
    for (int c = 0; c < 6; ++c)
#pragma unroll
      for (int mf = 0; mf < 4; ++mf) {
        const int row = mf * 16 + lr;
        const unsigned off =
            ((unsigned)(c * 64 + lhi * 16)) ^ ((unsigned)((row & 7) << 4));
        const bx8 kf =
            *(const bx8*)((const char*)Ks + (size_t)row * 384 + off);
        st[mf] = mfma16(kf, qf[c], st[mf]);
      }
    __builtin_amdgcn_s_setprio(0);
    float pvv[16];
#pragma unroll
    for (int mf = 0; mf < 4; ++mf)
#pragma unroll
      for (int r = 0; r < 4; ++r) {
        float s = st[mf][r] * scale;
        if (diag && (k0 + mf * 16 + lhi * 4 + r > qg)) s = -INFINITY;
        pvv[mf * 4 + r] = s;
      }
    float mx = pvv[0];
#pragma unroll
    for (int tt = 1; tt < 16; ++tt) mx = fmaxf(mx, pvv[tt]);
    mx = fmaxf(mx, __shfl_xor(mx, 16, 64));
    mx = fmaxf(mx, __shfl_xor(mx, 32, 64));
    const bool skip = __all(mx - m_run <= 8.0f);
    if (!skip) {
      const float mnew = fmaxf(m_run, mx);
      const float alpha = __expf(m_run - mnew);
      float afr[4];
#pragma unroll
      for (int r = 0; r < 4; ++r) afr[r] = __shfl(alpha, lhi * 4 + r, 64);
#pragma unroll
      for (int nf = 0; nf < 12; ++nf)
#pragma unroll
        for (int r = 0; r < 4; ++r) acc[nf][r] *= afr[r];
      l_run *= alpha;
      m_run = mnew;
    }
    float rs = 0.f;
#pragma unroll
    for (int tt = 0; tt < 16; ++tt) {
      const float e = __expf(pvv[tt] - m_run);
      pvv[tt] = e;
      rs += e;
    }
    rs += __shfl_xor(rs, 16, 64);
    rs += __shfl_xor(rs, 32, 64);
    l_run += rs;
    // pi-permuted A-fragments: lane-local, no LDS, no shuffles.
    u16x8 pa0, pa1;
#pragma unroll
    for (int j = 0; j < 8; ++j) {
      pa0[j] = f32_bf16(pvv[j]);
      pa1[j] = f32_bf16(pvv[8 + j]);
    }
    const bx8 pf0 = __builtin_bit_cast(bx8, pa0);
    const bx8 pf1 = __builtin_bit_cast(bx8, pa1);
#pragma unroll
    for (int gg = 0; gg < 3; ++gg) {
      u16x4 tl[4][2], th[4][2];
#pragma unroll
      for (int q4 = 0; q4 < 4; ++q4)
#pragma unroll
        for (int c2 = 0; c2 < 2; ++c2) {
          const int nf = gg * 4 + q4;
          const unsigned va =
              vlds0 + (unsigned)((nf * 16 + c2 * 8 + lhi * 2) * 128 + lr * 8);
          asm volatile("ds_read_b64_tr_b16 %0, %2\n\t"
                       "ds_read_b64_tr_b16 %1, %2 offset:128"
                       : "=&v"(tl[q4][c2]), "=&v"(th[q4][c2])
                       : "v"(va));
        }
      asm volatile("s_waitcnt lgkmcnt(0)" ::: "memory");
      __builtin_amdgcn_sched_barrier(0);
      __builtin_amdgcn_s_setprio(1);
#pragma unroll
      for (int q4 = 0; q4 < 4; ++q4)
#pragma unroll
        for (int c2 = 0; c2 < 2; ++c2) {
          const int nf = gg * 4 + q4;
          const u16x8 vv = __builtin_shufflevector(tl[q4][c2], th[q4][c2], 0,
                                                   1, 2, 3, 4, 5, 6, 7);
          acc[nf] = mfma16(c2 == 0 ? pf0 : pf1, __builtin_bit_cast(bx8, vv),
                           acc[nf]);
        }
      __builtin_amdgcn_s_setprio(0);
    }
  };

  auto run = [&](int qt, int i0, int i1) {
    m_run = -INFINITY;
    l_run = 0.f;
#pragma unroll
    for (int nf = 0; nf < 12; ++nf) acc[nf] = zero;
    qload(qt);
    ldregs(i0);
    for (int i = i0; i <= i1; ++i) {
      bar_bare();  // previous tile's LDS reads consumed before arrival
#pragma unroll
      for (int r = 0; r < 6; ++r) {
        *(u16x8*)&Ks[(size_t)(tid + r * 256) * 8] = kreg[r];
        *(u16x8*)&Vs[(size_t)(tid + r * 256) * 8] = vreg[r];
      }
      if (i < i1) ldregs(i + 1);  // stays in flight across bar_lgkm
      bar_lgkm();  // ds_writes visible; prefetch NOT drained
      compute(i, qt);
    }
  };

  auto final_epilogue = [&](int qt) {
#pragma unroll
    for (int r = 0; r < 4; ++r) {
      const float lb = __shfl(l_run, lhi * 4 + r, 64);
      const float linv = 1.0f / lb;
      const size_t orow =
          base_elem + (size_t)(qt * 64 + wave * 16 + lhi * 4 + r) * CD;
#pragma unroll
      for (int nf = 0; nf < 12; ++nf)
        Og[orow + nf * 16 + lr] = f32_bf16(acc[nf][r] * linv);
    }
  };

  auto partial_epilogue = [&](u16* pO, float* pML) {
    if (lhi == 0) {
      pML[slot * 128 + wave * 16 + lr] = m_run;
      pML[slot * 128 + 64 + wave * 16 + lr] = l_run;
    }
#pragma unroll
    for (int r = 0; r < 4; ++r) {
      const float lb = __shfl(l_run, lhi * 4 + r, 64);
      const float linv = 1.0f / lb;
      u16* dst =
          pO + (size_t)slot * 12288 + (size_t)(wave * 16 + lhi * 4 + r) * 192;
#pragma unroll
      for (int nf = 0; nf < 12; ++nf)
        dst[nf * 16 + lr] = f32_bf16(acc[nf][r] * linv);
    }
  };

  if (roleB) {
    run(qtHi, 15 - t, 31 - t);
    partial_epilogue(pbO, pbML);
  } else {
    run(qtLo, 0, t);
    final_epilogue(qtLo);
    if (t < 15) {
      run(qtHi, 0, 14 - t);
      partial_epilogue(paO, paML);
    } else {
      // empty prefix: mark zero-weight partial (paO slot left unwritten;
      // combine_qt must NEVER read it -- scratch may hold NaN bit patterns)
      if (tid < 64) {
        paML[slot * 128 + tid] = -1e30f;
        paML[slot * 128 + 64 + tid] = 0.f;
      }
    }
  }
}

// ---------------------------------------------------------------- combine
// Merge A/B partials for qtHi tiles (qt 16..31) into preout.
// lA==0 (empty-prefix marker): copy B partial WITHOUT touching paO -- its
// slot is uninitialized scratch in d_out; 0*NaN = NaN would leak otherwise
// (this was the r5 replay-determinism bug).
__global__ void __launch_bounds__(256) combine_qt(
    const u16* __restrict__ paO, const float* __restrict__ paML,
    const u16* __restrict__ pbO, const float* __restrict__ pbML,
    u16* __restrict__ Og) {
  const int s = blockIdx.x;
  const int bh = s >> 4;
  const int qtHi = 16 + (s & 15);
  const int b = bh >> 2, h = bh & 3;
  const int tid = threadIdx.x;
  const int row = tid >> 2, cg = tid & 3;
  const float mA = paML[s * 128 + row], lA = paML[s * 128 + 64 + row];
  const float mB = pbML[s * 128 + row], lB = pbML[s * 128 + 64 + row];
  const size_t obase =
      ((size_t)b * CS + (size_t)qtHi * 64 + row) * CD + h * CDH + cg * 48;
  const u16* pa = paO + (size_t)s * 12288 + (size_t)row * 192 + cg * 48;
  const u16* pb = pbO + (size_t)s * 12288 + (size_t)row * 192 + cg * 48;
  if (lA > 0.f) {
    const float M = fmaxf(mA, mB);
    const float wA = lA * __expf(mA - M), wB = lB * __expf(mB - M);
    const float inv = 1.0f / (wA + wB);
    const float fa = wA * inv, fb = wB * inv;
#pragma unroll
    for (int c = 0; c < 6; ++c) {
      const u16x8 va = *(const u16x8*)&pa[c * 8];
      const u16x8 vb = *(const u16x8*)&pb[c * 8];
      u16x8 o;
#pragma unroll
      for (int j = 0; j < 8; ++j)
        o[j] = f32_bf16(fa * bf16_f32(va[j]) + fb * bf16_f32(vb[j]));
      *(u16x8*)&Og[obase + c * 8] = o;
    }
  } else {
#pragma unroll
    for (int c = 0; c < 6; ++c)
      *(u16x8*)&Og[obase + c * 8] = *(const u16x8*)&pb[c * 8];
  }
}

// ---------------------------------------------------------------- launch
extern "C" void kernel_launch(void* const* d_in, const int* in_sizes, int n_in,
                              void* d_out, int out_size, void* d_ws,
                              size_t ws_size, hipStream_t stream) {
  (void)in_sizes;
  (void)n_in;
  (void)out_size;
  (void)ws_size;
  const float* x = (const float*)d_in[0];
  const float* wq = (const float*)d_in[1];
  const float* wk = (const float*)d_in[2];
  const float* wv = (const float*)d_in[3];
  const float* wo = (const float*)d_in[4];
  float* out = (float*)d_out;
  char* ws = (char*)d_ws;
  const size_t big = (size_t)CM * CD * 2;  // 12,582,912 B
  const size_t wsz = (size_t)CD * CD * 2;  // 1,179,648 B
  u16* xb = (u16*)ws;  // reused as preout after QKV gemm
  u16* qb = (u16*)(ws + big);
  u16* kb = (u16*)(ws + 2 * big);
  u16* vb = (u16*)(ws + 3 * big);
  u16* wqb = (u16*)(ws + 4 * big);
  u16* wkb = (u16*)(ws + 4 * big + wsz);
  u16* wvb = (u16*)(ws + 4 * big + 2 * wsz);
  u16* wob = (u16*)(ws + 4 * big + 3 * wsz);
  u16* pob = xb;
  // partial scratch lives in d_out (25 MB f32), overwritten by final GEMM
  const size_t pOsz = (size_t)256 * 64 * 192 * 2;  // 6,291,456 B
  u16* paO = (u16*)d_out;
  u16* pbO = (u16*)((char*)d_out + pOsz);
  float* paML = (float*)((char*)d_out + 2 * pOsz);
  float* pbML = (float*)((char*)d_out + 2 * pOsz + 131072);

  convert_all<<<dim3(2048), dim3(256), 0, stream>>>(x, wq, wk, wv, wo, xb, wqb,
                                                    wkb, wvb, wob);
  gemm_bt<true><<<dim3(64, 6, 3), dim3(256), 0, stream>>>(
      xb, wqb, wkb, wvb, (void*)qb, (void*)kb, (void*)vb, CM, CD, CD);
  flash_attn<<<dim3(512), dim3(256), 0, stream>>>(qb, kb, vb, pob, paO, paML,
                                                  pbO, pbML);
  combine_qt<<<dim3(256), dim3(256), 0, stream>>>(paO, paML, pbO, pbML, pob);
  gemm_bt<false><<<dim3(64, 6, 1), dim3(256), 0, stream>>>(
      pob, wob, wob, wob, (void*)out, (void*)out, (void*)out, CM, CD, CD);
}

// Round 23
// 132.200 us; speedup vs baseline: 1.1115x; 1.0019x over previous
//
#include <hip/hip_runtime.h>
#include <hip/hip_bf16.h>

// Shapes (fixed by the problem)
constexpr int CB = 4, CS = 2048, CD = 768, CH = 4, CDH = 192;
constexpr int CM = CB * CS;  // 8192 rows

typedef float f32x4 __attribute__((ext_vector_type(4)));
typedef float fx4 __attribute__((ext_vector_type(4)));
typedef __bf16 bx8 __attribute__((ext_vector_type(8)));
typedef unsigned short u16;
typedef u16 u16x8 __attribute__((ext_vector_type(8)));
typedef u16 u16x4 __attribute__((ext_vector_type(4)));

static __device__ __forceinline__ u16 f32_bf16(float f) {
  unsigned u = __builtin_bit_cast(unsigned, f);
  u += 0x7FFFu + ((u >> 16) & 1u);
  return (u16)(u >> 16);
}
static __device__ __forceinline__ float bf16_f32(u16 v) {
  return __builtin_bit_cast(float, (unsigned)v << 16);
}

static __device__ __forceinline__ f32x4 mfma16(bx8 a, bx8 b, f32x4 c) {
  return __builtin_amdgcn_mfma_f32_16x16x32_bf16(a, b, c, 0, 0, 0);
}

// Raw barriers (T4, proven r12): __syncthreads() emits s_waitcnt vmcnt(0)
// lgkmcnt(0) before s_barrier, draining in-flight global prefetch.
static __device__ __forceinline__ void bar_bare() {
  __builtin_amdgcn_s_barrier();
  __builtin_amdgcn_sched_barrier(0);
}
static __device__ __forceinline__ void bar_lgkm() {
  asm volatile("s_waitcnt lgkmcnt(0)" ::: "memory");
  __builtin_amdgcn_s_barrier();
  __builtin_amdgcn_sched_barrier(0);
}

// ---------------------------------------------------------------- convert
// r23: 16B/lane on BOTH sides (G13): 2x fx4 loads -> 1x u16x8 store per
// thread-iter (was fx4 load + u16x4 8B store -> measured only ~4 TB/s).
// All segment sizes divide by 8 -> no tail.
__global__ void __launch_bounds__(256) convert_all(
    const float* __restrict__ x, const float* __restrict__ wq,
    const float* __restrict__ wk, const float* __restrict__ wv,
    const float* __restrict__ wo, u16* __restrict__ xb, u16* __restrict__ wqb,
    u16* __restrict__ wkb, u16* __restrict__ wvb, u16* __restrict__ wob) {
  const float* srcs[5] = {x, wq, wk, wv, wo};
  u16* dsts[5] = {xb, wqb, wkb, wvb, wob};
  const int n8s[5] = {CM * CD / 8, CD * CD / 8, CD * CD / 8, CD * CD / 8,
                      CD * CD / 8};
  const int gsz = gridDim.x * blockDim.x;
  const int gid = blockIdx.x * blockDim.x + threadIdx.x;
#pragma unroll
  for (int sg = 0; sg < 5; ++sg) {
    const fx4* src = (const fx4*)srcs[sg];
    u16* dst = dsts[sg];
    const int n8 = n8s[sg];
    for (int i = gid; i < n8; i += gsz) {
      const fx4 a = src[2 * i];
      const fx4 b = src[2 * i + 1];
      u16x8 o;
      o[0] = f32_bf16(a[0]);
      o[1] = f32_bf16(a[1]);
      o[2] = f32_bf16(a[2]);
      o[3] = f32_bf16(a[3]);
      o[4] = f32_bf16(b[0]);
      o[5] = f32_bf16(b[1]);
      o[6] = f32_bf16(b[2]);
      o[7] = f32_bf16(b[3]);
      *(u16x8*)&dst[(size_t)i * 8] = o;
    }
  }
}

// ---------------------------------------------------------------- GEMM
// r12 version (best measured): 128x128 tile, reg-prefetch + raw barriers.
// Closed: gload_lds (r10, -6us), launch_bounds(,3) (r19, neutral),
// 128x64 tile (r20, -3us).
template <bool OUT_BF16>
__global__ void __launch_bounds__(256) gemm_bt(
    const u16* __restrict__ A, const u16* __restrict__ Bw0,
    const u16* __restrict__ Bw1, const u16* __restrict__ Bw2,
    void* __restrict__ C0, void* __restrict__ C1, void* __restrict__ C2,
    int M, int N, int K) {
  constexpr int LDK = 72;
  __shared__ u16 As[128][LDK];
  __shared__ u16 Bs[128][LDK];
  const int z = blockIdx.z;
  const u16* Bw = (z == 0) ? Bw0 : ((z == 1) ? Bw1 : Bw2);
  void* Cv = (z == 0) ? C0 : ((z == 1) ? C1 : C2);
  const int m0 = blockIdx.x * 128;
  const int n0 = blockIdx.y * 128;
  const int tid = threadIdx.x;
  const int wave = tid >> 6, lane = tid & 63;
  const int wr = wave >> 1, wc = wave & 1;
  const int lr = lane & 15, lhi = lane >> 4;

  f32x4 acc[4][4];
  const f32x4 zero = {0.f, 0.f, 0.f, 0.f};
#pragma unroll
  for (int i = 0; i < 4; ++i)
#pragma unroll
    for (int j = 0; j < 4; ++j) acc[i][j] = zero;

  u16x8 areg[4], breg[4];
  auto ldregs = [&](int kk) {
#pragma unroll
    for (int r = 0; r < 4; ++r) {
      const int id = tid + r * 256;
      const int row = id >> 3, ch = id & 7;
      areg[r] = *(const u16x8*)&A[(size_t)(m0 + row) * K + kk + ch * 8];
      breg[r] = *(const u16x8*)&Bw[(size_t)(n0 + row) * K + kk + ch * 8];
    }
  };

  ldregs(0);
  for (int kk = 0; kk < K; kk += 64) {
    bar_bare();
#pragma unroll
    for (int r = 0; r < 4; ++r) {
      const int id = tid + r * 256;
      const int row = id >> 3, ch = id & 7;
      *(u16x8*)&As[row][ch * 8] = areg[r];
      *(u16x8*)&Bs[row][ch * 8] = breg[r];
    }
    if (kk + 64 < K) ldregs(kk + 64);
    bar_lgkm();
#pragma unroll
    for (int ks = 0; ks < 2; ++ks) {
      bx8 af[4], bf[4];
#pragma unroll
      for (int mf = 0; mf < 4; ++mf)
        af[mf] = *(const bx8*)&As[wr * 64 + mf * 16 + lr][ks * 32 + lhi * 8];
#pragma unroll
      for (int nf = 0; nf < 4; ++nf)
        bf[nf] = *(const bx8*)&Bs[wc * 64 + nf * 16 + lr][ks * 32 + lhi * 8];
      __builtin_amdgcn_s_setprio(1);
#pragma unroll
      for (int mf = 0; mf < 4; ++mf)
#pragma unroll
        for (int nf = 0; nf < 4; ++nf)
          acc[mf][nf] = mfma16(af[mf], bf[nf], acc[mf][nf]);
      __builtin_amdgcn_s_setprio(0);
    }
  }
#pragma unroll
  for (int mf = 0; mf < 4; ++mf)
#pragma unroll
    for (int nf = 0; nf < 4; ++nf)
#pragma unroll
      for (int r = 0; r < 4; ++r) {
        const int row = m0 + wr * 64 + mf * 16 + lhi * 4 + r;
        const int col = n0 + wc * 64 + nf * 16 + lr;
        if constexpr (OUT_BF16)
          ((u16*)Cv)[(size_t)row * N + col] = f32_bf16(acc[mf][nf][r]);
        else
          ((float*)Cv)[(size_t)row * N + col] = acc[mf][nf][r];
      }
}

// ---------------------------------------------------------------- flash attn
// r15 (best measured): pi-permuted PV (no P LDS roundtrip), reg-staged,
// raw barriers, 512 equal-length blocks, XCD remap (T1). Closed as
// neutral/worse: QBLK=128 (r11/r21), occupancy-via-cap (r13/r14 spills),
// gload_lds staging (r10/r16), K-dbuf (r9/r18), finer split (r17).
// Invariant: P[q][k] x V[k][d] unchanged under k-permutation applied to both
// P and V. pi(mf*16+lhi*4+r) = lhi*8+(mf&1)*4+r+(mf>>1)*32 makes lane
// (lhi,lr)'s 16 post-softmax values its PV A-fragment in order; V staged
// with inverse-pi'd row offsets (vOff only). LDS 49,152 B.
__global__ void __launch_bounds__(256, 2) flash_attn(
    const u16* __restrict__ Qg, const u16* __restrict__ Kg,
    const u16* __restrict__ Vg, u16* __restrict__ Og, u16* __restrict__ paO,
    float* __restrict__ paML, u16* __restrict__ pbO,
    float* __restrict__ pbML) {
  __shared__ u16 Ks[12288];
  __shared__ u16 Vs[12288];
  const int i0_ = blockIdx.x;
  const int xcd = i0_ & 7;        // presumed XCD (block -> XCD = id % 8)
  const int j_ = i0_ >> 3;        // 0..63 within XCD
  const int bh = xcd * 2 + (j_ >> 5);
  const int jj = j_ & 31;
  const int t = jj >> 1;
  const int roleB = jj & 1;
  const int qtLo = t, qtHi = 31 - t;
  const int slot = bh * 16 + (15 - t);
  const int b = bh >> 2, h = bh & 3;
  const int tid = threadIdx.x;
  const int wave = tid >> 6, lane = tid & 63;
  const int lr = lane & 15, lhi = lane >> 4;
  const size_t base_elem = ((size_t)b * CS) * CD + (size_t)h * CDH;
  constexpr float scale = 0.07216878364870323f;  // 1/sqrt(192)
  const f32x4 zero = {0.f, 0.f, 0.f, 0.f};

  // per-thread staging offsets (within a KV tile), elements.
  // K: linear dest + inverse-XOR-swizzled source (rule #21).
  // V: subtiled 4k x 16d dest; source row = pi^{-1}(position) so that the
  //    tr-read's position axis is the pi-permuted k axis.
  int kOff[6], vOff[6];
#pragma unroll
  for (int r = 0; r < 6; ++r) {
    const int p = tid + r * 256;
    {
      const int k = p / 24, c16 = p - k * 24;
      const unsigned swz = ((unsigned)(c16 * 16)) ^ ((unsigned)((k & 7) << 4));
      kOff[r] = k * CD + (int)(swz >> 1);
    }
    {
      const int blk = p >> 3, kq = (p >> 1) & 3, dh = p & 1;
      const int kpos = ((blk & 15) << 2) + kq;  // position in pi space
      // k = pi^{-1}(kpos): pos bits b32|l|m1|r -> k = (b32*2+m1)*16 + l*4 + r
      const int kglob = (((kpos >> 5) * 2 + ((kpos >> 2) & 1)) << 4) +
                        (((kpos >> 3) & 3) << 2) + (kpos & 3);
      const int d = ((blk >> 4) << 4) + dh * 8;
      vOff[r] = kglob * CD + d;
    }
  }
  const unsigned vlds0 =
      (unsigned)(unsigned long long)(__attribute__((address_space(3)))
                                         u16*)&Vs[0];

  float m_run, l_run;
  f32x4 acc[12];
  bx8 qf[6];
  u16x8 kreg[6], vreg[6];

  auto qload = [&](int qt) {
    const size_t qoff = base_elem + (size_t)(qt * 64 + wave * 16 + lr) * CD;
#pragma unroll
    for (int c = 0; c < 6; ++c)
      qf[c] = *(const bx8*)&Qg[qoff + c * 32 + lhi * 8];
  };

  auto ldregs = [&](int kt) {
    const u16* kg = Kg + base_elem + (size_t)(kt * 64) * CD;
    const u16* vg = Vg + base_elem + (size_t)(kt * 64) * CD;
#pragma unroll
    for (int r = 0; r < 6; ++r) {
      kreg[r] = *(const u16x8*)&kg[kOff[r]];
      vreg[r] = *(const u16x8*)&vg[vOff[r]];
    }
  };

  auto compute = [&](int i, int qt) {
    const int qg = qt * 64 + wave * 16 + lr;
    const int k0 = i * 64;
    const bool diag = (i == qt);
    f32x4 st[4];
#pragma unroll
    for (int mf = 0; mf < 4; ++mf) st[mf] = zero;
    __builtin_amdgcn_s_setprio(1);
#pragma unroll
    for (int c = 0; c < 6; ++c)
#pragma unroll
      for (int mf = 0; mf < 4; ++mf) {
        const int row = mf * 16 + lr;
        const unsigned off =
            ((unsigned)(c * 64 + lhi * 16)) ^ ((unsigned)((row & 7) << 4));
        const bx8 kf =
            *(const bx8*)((const char*)Ks + (size_t)row * 384 + off);
        st[mf] = mfma16(kf, qf[c], st[mf]);
      }
    __builtin_amdgcn_s_setprio(0);
    float pvv[16];
#pragma unroll
    for (int mf = 0; mf < 4; ++mf)
#pragma unroll
      for (int r = 0; r < 4; ++r) {
        float s = st[mf][r] * scale;
        if (diag && (k0 + mf * 16 + lhi * 4 + r > qg)) s = -INFINITY;
        pvv[mf * 4 + r] = s;
      }
    float mx = pvv[0];
#pragma unroll
    for (int tt = 1; tt < 16; ++tt) mx = fmaxf(mx, pvv[tt]);
    mx = fmaxf(mx, __shfl_xor(mx, 16, 64));
    mx = fmaxf(mx, __shfl_xor(mx, 32, 64));
    const bool skip = __all(mx - m_run <= 8.0f);
    if (!skip) {
      const float mnew = fmaxf(m_run, mx);
      const float alpha = __expf(m_run - mnew);
      float afr[4];
#pragma unroll
      for (int r = 0; r < 4; ++r) afr[r] = __shfl(alpha, lhi * 4 + r, 64);
#pragma unroll
      for (int nf = 0; nf < 12; ++nf)
#pragma unroll
        for (int r = 0; r < 4; ++r) acc[nf][r] *= afr[r];
      l_run *= alpha;
      m_run = mnew;
    }
    float rs = 0.f;
#pragma unroll
    for (int tt = 0; tt < 16; ++tt) {
      const float e = __expf(pvv[tt] - m_run);
      pvv[tt] = e;
      rs += e;
    }
    rs += __shfl_xor(rs, 16, 64);
    rs += __shfl_xor(rs, 32, 64);
    l_run += rs;
    // pi-permuted A-fragments: lane-local, no LDS, no shuffles.
    u16x8 pa0, pa1;
#pragma unroll
    for (int j = 0; j < 8; ++j) {
      pa0[j] = f32_bf16(pvv[j]);
      pa1[j] = f32_bf16(pvv[8 + j]);
    }
    const bx8 pf0 = __builtin_bit_cast(bx8, pa0);
    const bx8 pf1 = __builtin_bit_cast(bx8, pa1);
#pragma unroll
    for (int gg = 0; gg < 3; ++gg) {
      u16x4 tl[4][2], th[4][2];
#pragma unroll
      for (int q4 = 0; q4 < 4; ++q4)
#pragma unroll
        for (int c2 = 0; c2 < 2; ++c2) {
          const int nf = gg * 4 + q4;
          const unsigned va =
              vlds0 + (unsigned)((nf * 16 + c2 * 8 + lhi * 2) * 128 + lr * 8);
          asm volatile("ds_read_b64_tr_b16 %0, %2\n\t"
                       "ds_read_b64_tr_b16 %1, %2 offset:128"
                       : "=&v"(tl[q4][c2]), "=&v"(th[q4][c2])
                       : "v"(va));
        }
      asm volatile("s_waitcnt lgkmcnt(0)" ::: "memory");
      __builtin_amdgcn_sched_barrier(0);
      __builtin_amdgcn_s_setprio(1);
#pragma unroll
      for (int q4 = 0; q4 < 4; ++q4)
#pragma unroll
        for (int c2 = 0; c2 < 2; ++c2) {
          const int nf = gg * 4 + q4;
          const u16x8 vv = __builtin_shufflevector(tl[q4][c2], th[q4][c2], 0,
                                                   1, 2, 3, 4, 5, 6, 7);
          acc[nf] = mfma16(c2 == 0 ? pf0 : pf1, __builtin_bit_cast(bx8, vv),
                           acc[nf]);
        }
      __builtin_amdgcn_s_setprio(0);
    }
  };

  auto run = [&](int qt, int i0, int i1) {
    m_run = -INFINITY;
    l_run = 0.f;
#pragma unroll
    for (int nf = 0; nf < 12; ++nf) acc[nf] = zero;
    qload(qt);
    ldregs(i0);
    for (int i = i0; i <= i1; ++i) {
      bar_bare();  // previous tile's LDS reads consumed before arrival
#pragma unroll
      for (int r = 0; r < 6; ++r) {
        *(u16x8*)&Ks[(size_t)(tid + r * 256) * 8] = kreg[r];
        *(u16x8*)&Vs[(size_t)(tid + r * 256) * 8] = vreg[r];
      }
      if (i < i1) ldregs(i + 1);  // stays in flight across bar_lgkm
      bar_lgkm();  // ds_writes visible; prefetch NOT drained
      compute(i, qt);
    }
  };

  auto final_epilogue = [&](int qt) {
#pragma unroll
    for (int r = 0; r < 4; ++r) {
      const float lb = __shfl(l_run, lhi * 4 + r, 64);
      const float linv = 1.0f / lb;
      const size_t orow =
          base_elem + (size_t)(qt * 64 + wave * 16 + lhi * 4 + r) * CD;
#pragma unroll
      for (int nf = 0; nf < 12; ++nf)
        Og[orow + nf * 16 + lr] = f32_bf16(acc[nf][r] * linv);
    }
  };

  auto partial_epilogue = [&](u16* pO, float* pML) {
    if (lhi == 0) {
      pML[slot * 128 + wave * 16 + lr] = m_run;
      pML[slot * 128 + 64 + wave * 16 + lr] = l_run;
    }
#pragma unroll
    for (int r = 0; r < 4; ++r) {
      const float lb = __shfl(l_run, lhi * 4 + r, 64);
      const float linv = 1.0f / lb;
      u16* dst =
          pO + (size_t)slot * 12288 + (size_t)(wave * 16 + lhi * 4 + r) * 192;
#pragma unroll
      for (int nf = 0; nf < 12; ++nf)
        dst[nf * 16 + lr] = f32_bf16(acc[nf][r] * linv);
    }
  };

  if (roleB) {
    run(qtHi, 15 - t, 31 - t);
    partial_epilogue(pbO, pbML);
  } else {
    run(qtLo, 0, t);
    final_epilogue(qtLo);
    if (t < 15) {
      run(qtHi, 0, 14 - t);
      partial_epilogue(paO, paML);
    } else {
      // empty prefix: mark zero-weight partial (paO slot left unwritten;
      // combine_qt must NEVER read it -- scratch may hold NaN bit patterns)
      if (tid < 64) {
        paML[slot * 128 + tid] = -1e30f;
        paML[slot * 128 + 64 + tid] = 0.f;
      }
    }
  }
}

// ---------------------------------------------------------------- combine
// Merge A/B partials for qtHi tiles (qt 16..31) into preout.
// lA==0 (empty-prefix marker): copy B partial WITHOUT touching paO -- its
// slot is uninitialized scratch in d_out; 0*NaN = NaN would leak otherwise
// (this was the r5 replay-determinism bug).
__global__ void __launch_bounds__(256) combine_qt(
    const u16* __restrict__ paO, const float* __restrict__ paML,
    const u16* __restrict__ pbO, const float* __restrict__ pbML,
    u16* __restrict__ Og) {
  const int s = blockIdx.x;
  const int bh = s >> 4;
  const int qtHi = 16 + (s & 15);
  const int b = bh >> 2, h = bh & 3;
  const int tid = threadIdx.x;
  const int row = tid >> 2, cg = tid & 3;
  const float mA = paML[s * 128 + row], lA = paML[s * 128 + 64 + row];
  const float mB = pbML[s * 128 + row], lB = pbML[s * 128 + 64 + row];
  const size_t obase =
      ((size_t)b * CS + (size_t)qtHi * 64 + row) * CD + h * CDH + cg * 48;
  const u16* pa = paO + (size_t)s * 12288 + (size_t)row * 192 + cg * 48;
  const u16* pb = pbO + (size_t)s * 12288 + (size_t)row * 192 + cg * 48;
  if (lA > 0.f) {
    const float M = fmaxf(mA, mB);
    const float wA = lA * __expf(mA - M), wB = lB * __expf(mB - M);
    const float inv = 1.0f / (wA + wB);
    const float fa = wA * inv, fb = wB * inv;
#pragma unroll
    for (int c = 0; c < 6; ++c) {
      const u16x8 va = *(const u16x8*)&pa[c * 8];
      const u16x8 vb = *(const u16x8*)&pb[c * 8];
      u16x8 o;
#pragma unroll
      for (int j = 0; j < 8; ++j)
        o[j] = f32_bf16(fa * bf16_f32(va[j]) + fb * bf16_f32(vb[j]));
      *(u16x8*)&Og[obase + c * 8] = o;
    }
  } else {
#pragma unroll
    for (int c = 0; c < 6; ++c)
      *(u16x8*)&Og[obase + c * 8] = *(const u16x8*)&pb[c * 8];
  }
}

// ---------------------------------------------------------------- launch
extern "C" void kernel_launch(void* const* d_in, const int* in_sizes, int n_in,
                              void* d_out, int out_size, void* d_ws,
                              size_t ws_size, hipStream_t stream) {
  (void)in_sizes;
  (void)n_in;
  (void)out_size;
  (void)ws_size;
  const float* x = (const float*)d_in[0];
  const float* wq = (const float*)d_in[1];
  const float* wk = (const float*)d_in[2];
  const float* wv = (const float*)d_in[3];
  const float* wo = (const float*)d_in[4];
  float* out = (float*)d_out;
  char* ws = (char*)d_ws;
  const size_t big = (size_t)CM * CD * 2;  // 12,582,912 B
  const size_t wsz = (size_t)CD * CD * 2;  // 1,179,648 B
  u16* xb = (u16*)ws;  // reused as preout after QKV gemm
  u16* qb = (u16*)(ws + big);
  u16* kb = (u16*)(ws + 2 * big);
  u16* vb = (u16*)(ws + 3 * big);
  u16* wqb = (u16*)(ws + 4 * big);
  u16* wkb = (u16*)(ws + 4 * big + wsz);
  u16* wvb = (u16*)(ws + 4 * big + 2 * wsz);
  u16* wob = (u16*)(ws + 4 * big + 3 * wsz);
  u16* pob = xb;
  // partial scratch lives in d_out (25 MB f32), overwritten by final GEMM
  const size_t pOsz = (size_t)256 * 64 * 192 * 2;  // 6,291,456 B
  u16* paO = (u16*)d_out;
  u16* pbO = (u16*)((char*)d_out + pOsz);
  float* paML = (float*)((char*)d_out + 2 * pOsz);
  float* pbML = (float*)((char*)d_out + 2 * pOsz + 131072);

  convert_all<<<dim3(2048), dim3(256), 0, stream>>>(x, wq, wk, wv, wo, xb, wqb,
                                                    wkb, wvb, wob);
  gemm_bt<true><<<dim3(64, 6, 3), dim3(256), 0, stream>>>(
      xb, wqb, wkb, wvb, (void*)qb, (void*)kb, (void*)vb, CM, CD, CD);
  flash_attn<<<dim3(512), dim3(256), 0, stream>>>(qb, kb, vb, pob, paO, paML,
                                                  pbO, pbML);
  combine_qt<<<dim3(256), dim3(256), 0, stream>>>(paO, paML, pbO, pbML, pob);
  gemm_bt<false><<<dim3(64, 6, 1), dim3(256), 0, stream>>>(
      pob, wob, wob, wob, (void*)out, (void*)out, (void*)out, CM, CD, CD);
}